// Round 9
// baseline (543.884 us; speedup 1.0000x reference)
//
#include <hip/hip_runtime.h>
#include <hip/hip_bf16.h>
#include <math.h>

#define N_NODES 100000
#define N_EDGES 1600000
#define IN_F 256
#define HID 32
#define OUTC 16
#define NBUCK 1000
#define BUCK_W 100     // NBUCK * BUCK_W == N_NODES
#define NBB 256        // partition blocks
#define CHUNK 6250     // N_EDGES / NBB

typedef unsigned short ushort_t;
typedef unsigned int uint_t;

__device__ inline ushort_t f2bf(float f) {
    union { float f; uint_t u; } v; v.f = f;
    uint_t r = v.u + 0x7fff + ((v.u >> 16) & 1);   // round-to-nearest-even
    return (ushort_t)(r >> 16);
}
__device__ inline float bf2f(ushort_t h) {
    union { uint_t u; float f; } v; v.u = (uint_t)h << 16;
    return v.f;
}
__device__ inline float bf_lo(uint_t d) {    // low bf16 of packed dword -> f32
    union { uint_t u; float f; } v; v.u = d << 16;
    return v.f;
}
__device__ inline float bf_hi(uint_t d) {    // high bf16 -> f32
    union { uint_t u; float f; } v; v.u = d & 0xFFFF0000u;
    return v.f;
}

// ============ Pass 1: per-block bucket histogram (LDS only) ============
__global__ __launch_bounds__(256) void k_cnt(const int* __restrict__ ei, int* __restrict__ bhist)
{
    __shared__ int lh[NBUCK];
    const int t = threadIdx.x;
    const int blk = blockIdx.x;
    for (int b = t; b < NBUCK; b += 256) lh[b] = 0;
    __syncthreads();
    const int base = blk * CHUNK;
    for (int i = t; i < CHUNK; i += 256) {
        const int dst = ei[N_EDGES + base + i];
        atomicAdd(&lh[dst / BUCK_W], 1);
    }
    __syncthreads();
    for (int b = t; b < NBUCK; b += 256) bhist[b * NBB + blk] = lh[b];
}

// ============ Pass 2a: scan each bucket's 256 block-counts ============
__global__ __launch_bounds__(256) void k_scanH(const int* __restrict__ bhist,
                                               int* __restrict__ boffB, int* __restrict__ btot)
{
    __shared__ int sh[256];
    const int t = threadIdx.x;
    const int b = blockIdx.x;
    const int v = bhist[b * NBB + t];
    sh[t] = v;
    __syncthreads();
    #pragma unroll
    for (int off = 1; off < 256; off <<= 1) {
        const int u = (t >= off) ? sh[t - off] : 0;
        __syncthreads();
        sh[t] += u;
        __syncthreads();
    }
    boffB[b * NBB + t] = sh[t] - v;
    if (t == 255) btot[b] = sh[255];
}

// ============ Pass 2b: scan bucket totals -> bucket start offsets ============
__global__ __launch_bounds__(1024) void k_scanH2(const int* __restrict__ btot,
                                                 int* __restrict__ bstart)
{
    __shared__ int sh[1024];
    const int t = threadIdx.x;
    const int v = (t < NBUCK) ? btot[t] : 0;
    sh[t] = v;
    __syncthreads();
    #pragma unroll
    for (int off = 1; off < 1024; off <<= 1) {
        const int u = (t >= off) ? sh[t - off] : 0;
        __syncthreads();
        sh[t] += u;
        __syncthreads();
    }
    if (t < NBUCK) bstart[t] = sh[t] - v;
    if (t == NBUCK - 1) bstart[NBUCK] = sh[t];
}

// ============ Pass 3: scatter edges into bucket-contiguous packed pairs ============
// pairsP[pos] = (dst % BUCK_W) << 17 | src   (src < 2^17, dstLocal < 2^7)
__global__ __launch_bounds__(256) void k_scat(const int* __restrict__ ei,
                                              const int* __restrict__ boffB,
                                              const int* __restrict__ bstart,
                                              int* __restrict__ pairsP)
{
    __shared__ int lcur[NBUCK];
    const int t = threadIdx.x;
    const int blk = blockIdx.x;
    for (int b = t; b < NBUCK; b += 256) lcur[b] = bstart[b] + boffB[b * NBB + blk];
    __syncthreads();
    const int base = blk * CHUNK;
    for (int i = t; i < CHUNK; i += 256) {
        const int src = ei[base + i];
        const int dst = ei[N_EDGES + base + i];
        const int b = dst / BUCK_W;
        const int pos = atomicAdd(&lcur[b], 1);
        pairsP[pos] = ((dst - b * BUCK_W) << 17) | src;
    }
}

// ============ Layer 1: h1 = x@W1a^T + b ; out1 = h1@W1b^T + b ============
__global__ __launch_bounds__(256) void k1_layer1_dense(
    const float* __restrict__ x,
    const float* __restrict__ w1a_w, const float* __restrict__ w1a_b,
    const float* __restrict__ w1b_w, const float* __restrict__ w1b_b,
    ushort_t* __restrict__ h1b, float* __restrict__ out1)
{
    __shared__ float ws[32][256];
    __shared__ float hs[256][36];
    __shared__ float wbs[32][32];

    const int t  = threadIdx.x;
    const int og = t & 3;
    const int ng = t >> 2;
    const int o0 = og * 8;
    const int node0 = blockIdx.x * 256;

    {
        const float4* wsrc = (const float4*)w1a_w;
        float4* wdst = (float4*)&ws[0][0];
        for (int i = t; i < 2048; i += 256) wdst[i] = wsrc[i];
        const float4* bsrc = (const float4*)w1b_w;
        float4* bdst = (float4*)&wbs[0][0];
        if (t < 256) bdst[t] = bsrc[t];
    }
    __syncthreads();

    int nid[4]; bool val[4];
    #pragma unroll
    for (int j = 0; j < 4; ++j) { nid[j] = node0 + ng * 4 + j; val[j] = nid[j] < N_NODES; }

    float acc[4][8] = {};
    for (int kc = 0; kc < 64; kc += 2) {
        float4 xs4[4][2];
        #pragma unroll
        for (int j = 0; j < 4; ++j) {
            if (val[j]) {
                const float4* xr = (const float4*)(x + (size_t)nid[j] * IN_F);
                xs4[j][0] = xr[kc];
                xs4[j][1] = xr[kc + 1];
            } else {
                xs4[j][0] = make_float4(0.f, 0.f, 0.f, 0.f);
                xs4[j][1] = make_float4(0.f, 0.f, 0.f, 0.f);
            }
        }
        #pragma unroll
        for (int u = 0; u < 2; ++u) {
            const int k4 = (kc + u) * 4;
            #pragma unroll
            for (int o = 0; o < 8; ++o) {
                const float4 w4 = *(const float4*)&ws[o0 + o][k4];
                #pragma unroll
                for (int j = 0; j < 4; ++j) {
                    acc[j][o] += xs4[j][u].x * w4.x + xs4[j][u].y * w4.y
                               + xs4[j][u].z * w4.z + xs4[j][u].w * w4.w;
                }
            }
        }
    }

    #pragma unroll
    for (int o = 0; o < 8; ++o) {
        const float b = w1a_b[o0 + o];
        #pragma unroll
        for (int j = 0; j < 4; ++j) acc[j][o] += b;
    }

    #pragma unroll
    for (int j = 0; j < 4; ++j) {
        const int ln = ng * 4 + j;
        *(float4*)&hs[ln][o0]     = make_float4(acc[j][0], acc[j][1], acc[j][2], acc[j][3]);
        *(float4*)&hs[ln][o0 + 4] = make_float4(acc[j][4], acc[j][5], acc[j][6], acc[j][7]);
        if (val[j]) {
            uint4 pk;
            pk.x = (uint_t)f2bf(acc[j][0]) | ((uint_t)f2bf(acc[j][1]) << 16);
            pk.y = (uint_t)f2bf(acc[j][2]) | ((uint_t)f2bf(acc[j][3]) << 16);
            pk.z = (uint_t)f2bf(acc[j][4]) | ((uint_t)f2bf(acc[j][5]) << 16);
            pk.w = (uint_t)f2bf(acc[j][6]) | ((uint_t)f2bf(acc[j][7]) << 16);
            *(uint4*)(h1b + (size_t)nid[j] * HID + o0) = pk;
        }
    }
    __syncthreads();

    float f[4][8] = {};
    #pragma unroll 2
    for (int c4 = 0; c4 < 8; ++c4) {
        float4 h4[4];
        #pragma unroll
        for (int j = 0; j < 4; ++j) h4[j] = *(const float4*)&hs[ng * 4 + j][c4 * 4];
        #pragma unroll
        for (int o = 0; o < 8; ++o) {
            const float4 w4 = *(const float4*)&wbs[o0 + o][c4 * 4];
            #pragma unroll
            for (int j = 0; j < 4; ++j)
                f[j][o] += h4[j].x * w4.x + h4[j].y * w4.y + h4[j].z * w4.z + h4[j].w * w4.w;
        }
    }
    #pragma unroll
    for (int o = 0; o < 8; ++o) {
        const float b = w1b_b[o0 + o];
        #pragma unroll
        for (int j = 0; j < 4; ++j) f[j][o] += b;
    }
    #pragma unroll
    for (int j = 0; j < 4; ++j) {
        if (val[j]) {
            float* dst = out1 + (size_t)nid[j] * HID + o0;
            *(float4*)dst       = make_float4(f[j][0], f[j][1], f[j][2], f[j][3]);
            *(float4*)(dst + 4) = make_float4(f[j][4], f[j][5], f[j][6], f[j][7]);
        }
    }
}

// ============ Aggregate layer 1: block = bucket; one edge per LANE ============
// Lane reads packed pair + the full 64B bf16 row (4x uint4 -> 64 rows in flight
// per wave instruction), then 32 ds_atomic_add into acc[rl*33 + c]
// (stride 33 -> bank = (rl+c)&31, uniform-random, ~2 lanes/bank = free).
__global__ __launch_bounds__(256) void k_agg32(const int* __restrict__ bstart,
                                               const int* __restrict__ pairsP,
                                               const ushort_t* __restrict__ h1b,
                                               float* __restrict__ out1)
{
    __shared__ float acc[BUCK_W * 33];     // 13.2 KB
    const int t = threadIdx.x;
    const int b = blockIdx.x;
    for (int i = t; i < BUCK_W * 33; i += 256) acc[i] = 0.f;
    __syncthreads();

    const int e0 = bstart[b];
    const int e1 = bstart[b + 1];
    for (int i = e0 + t; i < e1; i += 256) {
        const int p  = pairsP[i];
        const int rl = p >> 17;
        const int s  = p & 0x1FFFF;
        const uint4* row = (const uint4*)(h1b + (size_t)s * HID);
        const uint4 q0 = row[0];
        const uint4 q1 = row[1];
        const uint4 q2 = row[2];
        const uint4 q3 = row[3];
        float* a = &acc[rl * 33];
        atomicAdd(&a[0],  bf_lo(q0.x)); atomicAdd(&a[1],  bf_hi(q0.x));
        atomicAdd(&a[2],  bf_lo(q0.y)); atomicAdd(&a[3],  bf_hi(q0.y));
        atomicAdd(&a[4],  bf_lo(q0.z)); atomicAdd(&a[5],  bf_hi(q0.z));
        atomicAdd(&a[6],  bf_lo(q0.w)); atomicAdd(&a[7],  bf_hi(q0.w));
        atomicAdd(&a[8],  bf_lo(q1.x)); atomicAdd(&a[9],  bf_hi(q1.x));
        atomicAdd(&a[10], bf_lo(q1.y)); atomicAdd(&a[11], bf_hi(q1.y));
        atomicAdd(&a[12], bf_lo(q1.z)); atomicAdd(&a[13], bf_hi(q1.z));
        atomicAdd(&a[14], bf_lo(q1.w)); atomicAdd(&a[15], bf_hi(q1.w));
        atomicAdd(&a[16], bf_lo(q2.x)); atomicAdd(&a[17], bf_hi(q2.x));
        atomicAdd(&a[18], bf_lo(q2.y)); atomicAdd(&a[19], bf_hi(q2.y));
        atomicAdd(&a[20], bf_lo(q2.z)); atomicAdd(&a[21], bf_hi(q2.z));
        atomicAdd(&a[22], bf_lo(q2.w)); atomicAdd(&a[23], bf_hi(q2.w));
        atomicAdd(&a[24], bf_lo(q3.x)); atomicAdd(&a[25], bf_hi(q3.x));
        atomicAdd(&a[26], bf_lo(q3.y)); atomicAdd(&a[27], bf_hi(q3.y));
        atomicAdd(&a[28], bf_lo(q3.z)); atomicAdd(&a[29], bf_hi(q3.z));
        atomicAdd(&a[30], bf_lo(q3.w)); atomicAdd(&a[31], bf_hi(q3.w));
    }
    __syncthreads();

    float* o = out1 + (size_t)b * BUCK_W * HID;
    for (int k = t; k < BUCK_W * HID; k += 256) {
        const int r = k >> 5, c = k & 31;
        o[k] += acc[r * 33 + c];
    }
}

// ============ Layer 2 dense ============
__global__ __launch_bounds__(256) void k3_layer2_dense(
    const float* __restrict__ out1,
    const float* __restrict__ w2a_w, const float* __restrict__ w2a_b,
    const float* __restrict__ w2b_w, const float* __restrict__ w2b_b,
    ushort_t* __restrict__ h2b, float* __restrict__ out2)
{
    __shared__ float rs[64][33];
    __shared__ float h2s[64][17];
    __shared__ float wa[16][33];
    __shared__ float wb[16][17];

    const int t = threadIdx.x;
    const int node0 = blockIdx.x * 64;
    const int nrem = N_NODES - node0;

    for (int i = t; i < 16 * 32; i += 256)
        wa[i >> 5][i & 31] = w2a_w[i];
    if (t < 16 * 16) wb[t >> 4][t & 15] = w2b_w[t];
    for (int i = t; i < 64 * 32; i += 256) {
        int r = i >> 5, c = i & 31;
        float v = 0.f;
        if (r < nrem) v = out1[(size_t)(node0 + r) * HID + c];
        rs[r][c] = fmaxf(v, 0.f);
    }
    __syncthreads();

    const int o = t & 15;
    const int g = t >> 4;

    const float ba = w2a_b[o];
    float acc[4] = {};
    for (int c = 0; c < 32; ++c) {
        const float w = wa[o][c];
        #pragma unroll
        for (int j = 0; j < 4; ++j) acc[j] += rs[g * 4 + j][c] * w;
    }
    #pragma unroll
    for (int j = 0; j < 4; ++j) {
        const int ln = g * 4 + j;
        const float v = acc[j] + ba;
        h2s[ln][o] = v;
        if (ln < nrem) h2b[(size_t)(node0 + ln) * OUTC + o] = f2bf(v);
    }
    __syncthreads();

    const float bbv = w2b_b[o];
    float f[4] = {};
    for (int c = 0; c < 16; ++c) {
        const float w = wb[o][c];
        #pragma unroll
        for (int j = 0; j < 4; ++j) f[j] += h2s[g * 4 + j][c] * w;
    }
    #pragma unroll
    for (int j = 0; j < 4; ++j) {
        const int ln = g * 4 + j;
        if (ln < nrem) out2[(size_t)(node0 + ln) * OUTC + o] = f[j] + bbv;
    }
}

// ============ Aggregate layer 2 (one edge per lane) + fused log_softmax ============
__global__ __launch_bounds__(256) void k_agg16_sm(const int* __restrict__ bstart,
                                                  const int* __restrict__ pairsP,
                                                  const ushort_t* __restrict__ h2b,
                                                  float* __restrict__ out2)
{
    __shared__ float acc[BUCK_W * 17];     // 6.8 KB
    const int t = threadIdx.x;
    const int b = blockIdx.x;
    for (int i = t; i < BUCK_W * 17; i += 256) acc[i] = 0.f;
    __syncthreads();

    const int e0 = bstart[b];
    const int e1 = bstart[b + 1];
    for (int i = e0 + t; i < e1; i += 256) {
        const int p  = pairsP[i];
        const int rl = p >> 17;
        const int s  = p & 0x1FFFF;
        const uint4* row = (const uint4*)(h2b + (size_t)s * OUTC);
        const uint4 q0 = row[0];
        const uint4 q1 = row[1];
        float* a = &acc[rl * 17];
        atomicAdd(&a[0],  bf_lo(q0.x)); atomicAdd(&a[1],  bf_hi(q0.x));
        atomicAdd(&a[2],  bf_lo(q0.y)); atomicAdd(&a[3],  bf_hi(q0.y));
        atomicAdd(&a[4],  bf_lo(q0.z)); atomicAdd(&a[5],  bf_hi(q0.z));
        atomicAdd(&a[6],  bf_lo(q0.w)); atomicAdd(&a[7],  bf_hi(q0.w));
        atomicAdd(&a[8],  bf_lo(q1.x)); atomicAdd(&a[9],  bf_hi(q1.x));
        atomicAdd(&a[10], bf_lo(q1.y)); atomicAdd(&a[11], bf_hi(q1.y));
        atomicAdd(&a[12], bf_lo(q1.z)); atomicAdd(&a[13], bf_hi(q1.z));
        atomicAdd(&a[14], bf_lo(q1.w)); atomicAdd(&a[15], bf_hi(q1.w));
    }
    __syncthreads();

    const int c = t & 15;
    const int grp = t >> 4;                // 16 row-groups
    const int nbase = b * BUCK_W;
    for (int r = grp; r < BUCK_W; r += 16) {
        const int n = nbase + r;
        const float val = out2[(size_t)n * OUTC + c] + acc[r * 17 + c];
        float m = val;
        #pragma unroll
        for (int off = 8; off > 0; off >>= 1)
            m = fmaxf(m, __shfl_xor(m, off, 16));
        float s = expf(val - m);
        #pragma unroll
        for (int off = 8; off > 0; off >>= 1)
            s += __shfl_xor(s, off, 16);
        const float lse = m + logf(s);
        out2[(size_t)n * OUTC + c] = val - lse;
    }
}

extern "C" void kernel_launch(void* const* d_in, const int* in_sizes, int n_in,
                              void* d_out, int out_size, void* d_ws, size_t ws_size,
                              hipStream_t stream)
{
    const float* x      = (const float*)d_in[0];
    const float* w1a_w  = (const float*)d_in[1];
    const float* w1a_b  = (const float*)d_in[2];
    const float* w1b_w  = (const float*)d_in[3];
    const float* w1b_b  = (const float*)d_in[4];
    const float* w2a_w  = (const float*)d_in[5];
    const float* w2a_b  = (const float*)d_in[6];
    const float* w2b_w  = (const float*)d_in[7];
    const float* w2b_b  = (const float*)d_in[8];
    const int*   ei     = (const int*)d_in[9];
    float* out = (float*)d_out;

    // workspace (~31 MB)
    float*    out1   = (float*)d_ws;                              // 12.8 MB
    ushort_t* h1b    = (ushort_t*)(out1 + (size_t)N_NODES * HID); // 6.4 MB
    ushort_t* h2b    = h1b + (size_t)N_NODES * HID;               // 3.2 MB
    int*      pairsP = (int*)(h2b + (size_t)N_NODES * OUTC);      // 6.4 MB
    int*      bhist  = pairsP + N_EDGES;                          // 1000*256 = 1 MB
    int*      boffB  = bhist + NBUCK * NBB;                       // 1 MB
    int*      btot   = boffB + NBUCK * NBB;                       // 1000
    int*      bstart = btot + NBUCK;                              // 1001

    k_cnt   <<<NBB, 256, 0, stream>>>(ei, bhist);
    k_scanH <<<NBUCK, 256, 0, stream>>>(bhist, boffB, btot);
    k_scanH2<<<1, 1024, 0, stream>>>(btot, bstart);
    k_scat  <<<NBB, 256, 0, stream>>>(ei, boffB, bstart, pairsP);

    k1_layer1_dense<<<(N_NODES + 255) / 256, 256, 0, stream>>>(x, w1a_w, w1a_b, w1b_w, w1b_b, h1b, out1);
    k_agg32<<<NBUCK, 256, 0, stream>>>(bstart, pairsP, h1b, out1);
    k3_layer2_dense<<<(N_NODES + 63) / 64, 256, 0, stream>>>(out1, w2a_w, w2a_b, w2b_w, w2b_b, h2b, out);
    k_agg16_sm<<<NBUCK, 256, 0, stream>>>(bstart, pairsP, h2b, out);
}

// Round 10
// 218.622 us; speedup vs baseline: 2.4878x; 2.4878x over previous
//
#include <hip/hip_runtime.h>
#include <hip/hip_bf16.h>
#include <math.h>

#define N_NODES 100000
#define N_EDGES 1600000
#define IN_F 256
#define HID 32
#define OUTC 16
#define NBUCK 1000
#define BUCK_W 100     // NBUCK * BUCK_W == N_NODES
#define NBB 256        // partition blocks
#define CHUNK 6250     // N_EDGES / NBB
#define MAXE 4096      // per-chunk edge capacity in LDS (buckets avg 1600, sd 40)

typedef unsigned short ushort_t;
typedef unsigned int uint_t;

__device__ inline ushort_t f2bf(float f) {
    union { float f; uint_t u; } v; v.f = f;
    uint_t r = v.u + 0x7fff + ((v.u >> 16) & 1);   // round-to-nearest-even
    return (ushort_t)(r >> 16);
}
__device__ inline float bf2f(ushort_t h) {
    union { uint_t u; float f; } v; v.u = (uint_t)h << 16;
    return v.f;
}

// ============ Pass 1: per-block bucket histogram (LDS only) ============
__global__ __launch_bounds__(256) void k_cnt(const int* __restrict__ ei, int* __restrict__ bhist)
{
    __shared__ int lh[NBUCK];
    const int t = threadIdx.x;
    const int blk = blockIdx.x;
    for (int b = t; b < NBUCK; b += 256) lh[b] = 0;
    __syncthreads();
    const int base = blk * CHUNK;
    for (int i = t; i < CHUNK; i += 256) {
        const int dst = ei[N_EDGES + base + i];
        atomicAdd(&lh[dst / BUCK_W], 1);
    }
    __syncthreads();
    for (int b = t; b < NBUCK; b += 256) bhist[b * NBB + blk] = lh[b];
}

// ============ Pass 2a: scan each bucket's 256 block-counts ============
__global__ __launch_bounds__(256) void k_scanH(const int* __restrict__ bhist,
                                               int* __restrict__ boffB, int* __restrict__ btot)
{
    __shared__ int sh[256];
    const int t = threadIdx.x;
    const int b = blockIdx.x;
    const int v = bhist[b * NBB + t];
    sh[t] = v;
    __syncthreads();
    #pragma unroll
    for (int off = 1; off < 256; off <<= 1) {
        const int u = (t >= off) ? sh[t - off] : 0;
        __syncthreads();
        sh[t] += u;
        __syncthreads();
    }
    boffB[b * NBB + t] = sh[t] - v;
    if (t == 255) btot[b] = sh[255];
}

// ============ Pass 2b: scan bucket totals -> bucket start offsets ============
__global__ __launch_bounds__(1024) void k_scanH2(const int* __restrict__ btot,
                                                 int* __restrict__ bstart)
{
    __shared__ int sh[1024];
    const int t = threadIdx.x;
    const int v = (t < NBUCK) ? btot[t] : 0;
    sh[t] = v;
    __syncthreads();
    #pragma unroll
    for (int off = 1; off < 1024; off <<= 1) {
        const int u = (t >= off) ? sh[t - off] : 0;
        __syncthreads();
        sh[t] += u;
        __syncthreads();
    }
    if (t < NBUCK) bstart[t] = sh[t] - v;
    if (t == NBUCK - 1) bstart[NBUCK] = sh[t];
}

// ============ Pass 3: scatter edges into bucket-contiguous packed pairs ============
// pairsP[pos] = (dst % BUCK_W) << 17 | src   (src < 2^17, dstLocal < 2^7)
__global__ __launch_bounds__(256) void k_scat(const int* __restrict__ ei,
                                              const int* __restrict__ boffB,
                                              const int* __restrict__ bstart,
                                              int* __restrict__ pairsP)
{
    __shared__ int lcur[NBUCK];
    const int t = threadIdx.x;
    const int blk = blockIdx.x;
    for (int b = t; b < NBUCK; b += 256) lcur[b] = bstart[b] + boffB[b * NBB + blk];
    __syncthreads();
    const int base = blk * CHUNK;
    for (int i = t; i < CHUNK; i += 256) {
        const int src = ei[base + i];
        const int dst = ei[N_EDGES + base + i];
        const int b = dst / BUCK_W;
        const int pos = atomicAdd(&lcur[b], 1);
        pairsP[pos] = ((dst - b * BUCK_W) << 17) | src;
    }
}

// ============ Layer 1: h1 = x@W1a^T + b ; out1 = h1@W1b^T + b ============
__global__ __launch_bounds__(256) void k1_layer1_dense(
    const float* __restrict__ x,
    const float* __restrict__ w1a_w, const float* __restrict__ w1a_b,
    const float* __restrict__ w1b_w, const float* __restrict__ w1b_b,
    ushort_t* __restrict__ h1b, float* __restrict__ out1)
{
    __shared__ float ws[32][256];
    __shared__ float hs[256][36];
    __shared__ float wbs[32][32];

    const int t  = threadIdx.x;
    const int og = t & 3;
    const int ng = t >> 2;
    const int o0 = og * 8;
    const int node0 = blockIdx.x * 256;

    {
        const float4* wsrc = (const float4*)w1a_w;
        float4* wdst = (float4*)&ws[0][0];
        for (int i = t; i < 2048; i += 256) wdst[i] = wsrc[i];
        const float4* bsrc = (const float4*)w1b_w;
        float4* bdst = (float4*)&wbs[0][0];
        if (t < 256) bdst[t] = bsrc[t];
    }
    __syncthreads();

    int nid[4]; bool val[4];
    #pragma unroll
    for (int j = 0; j < 4; ++j) { nid[j] = node0 + ng * 4 + j; val[j] = nid[j] < N_NODES; }

    float acc[4][8] = {};
    for (int kc = 0; kc < 64; kc += 2) {
        float4 xs4[4][2];
        #pragma unroll
        for (int j = 0; j < 4; ++j) {
            if (val[j]) {
                const float4* xr = (const float4*)(x + (size_t)nid[j] * IN_F);
                xs4[j][0] = xr[kc];
                xs4[j][1] = xr[kc + 1];
            } else {
                xs4[j][0] = make_float4(0.f, 0.f, 0.f, 0.f);
                xs4[j][1] = make_float4(0.f, 0.f, 0.f, 0.f);
            }
        }
        #pragma unroll
        for (int u = 0; u < 2; ++u) {
            const int k4 = (kc + u) * 4;
            #pragma unroll
            for (int o = 0; o < 8; ++o) {
                const float4 w4 = *(const float4*)&ws[o0 + o][k4];
                #pragma unroll
                for (int j = 0; j < 4; ++j) {
                    acc[j][o] += xs4[j][u].x * w4.x + xs4[j][u].y * w4.y
                               + xs4[j][u].z * w4.z + xs4[j][u].w * w4.w;
                }
            }
        }
    }

    #pragma unroll
    for (int o = 0; o < 8; ++o) {
        const float b = w1a_b[o0 + o];
        #pragma unroll
        for (int j = 0; j < 4; ++j) acc[j][o] += b;
    }

    #pragma unroll
    for (int j = 0; j < 4; ++j) {
        const int ln = ng * 4 + j;
        *(float4*)&hs[ln][o0]     = make_float4(acc[j][0], acc[j][1], acc[j][2], acc[j][3]);
        *(float4*)&hs[ln][o0 + 4] = make_float4(acc[j][4], acc[j][5], acc[j][6], acc[j][7]);
        if (val[j]) {
            uint4 pk;
            pk.x = (uint_t)f2bf(acc[j][0]) | ((uint_t)f2bf(acc[j][1]) << 16);
            pk.y = (uint_t)f2bf(acc[j][2]) | ((uint_t)f2bf(acc[j][3]) << 16);
            pk.z = (uint_t)f2bf(acc[j][4]) | ((uint_t)f2bf(acc[j][5]) << 16);
            pk.w = (uint_t)f2bf(acc[j][6]) | ((uint_t)f2bf(acc[j][7]) << 16);
            *(uint4*)(h1b + (size_t)nid[j] * HID + o0) = pk;
        }
    }
    __syncthreads();

    float f[4][8] = {};
    #pragma unroll 2
    for (int c4 = 0; c4 < 8; ++c4) {
        float4 h4[4];
        #pragma unroll
        for (int j = 0; j < 4; ++j) h4[j] = *(const float4*)&hs[ng * 4 + j][c4 * 4];
        #pragma unroll
        for (int o = 0; o < 8; ++o) {
            const float4 w4 = *(const float4*)&wbs[o0 + o][c4 * 4];
            #pragma unroll
            for (int j = 0; j < 4; ++j)
                f[j][o] += h4[j].x * w4.x + h4[j].y * w4.y + h4[j].z * w4.z + h4[j].w * w4.w;
        }
    }
    #pragma unroll
    for (int o = 0; o < 8; ++o) {
        const float b = w1b_b[o0 + o];
        #pragma unroll
        for (int j = 0; j < 4; ++j) f[j][o] += b;
    }
    #pragma unroll
    for (int j = 0; j < 4; ++j) {
        if (val[j]) {
            float* dst = out1 + (size_t)nid[j] * HID + o0;
            *(float4*)dst       = make_float4(f[j][0], f[j][1], f[j][2], f[j][3]);
            *(float4*)(dst + 4) = make_float4(f[j][4], f[j][5], f[j][6], f[j][7]);
        }
    }
}

// ============ Aggregate layer 1: block = bucket; in-LDS counting sort by node,
// then register-accumulated gather (NO atomics in the hot phase) ============
__global__ __launch_bounds__(256) void k_agg32(const int* __restrict__ bstart,
                                               const int* __restrict__ pairsP,
                                               const ushort_t* __restrict__ h1b,
                                               float* __restrict__ out1)
{
    __shared__ int cnt[128];
    __shared__ int off[129];
    __shared__ int srt[MAXE];
    const int t = threadIdx.x;
    const int b = blockIdx.x;
    const int c = t & 31;
    const int grp = t >> 5;                 // 8 groups of 32 lanes

    const int e0g = bstart[b];
    const int e1g = bstart[b + 1];

    for (int ch0 = e0g; ch0 < e1g; ch0 += MAXE) {
        const int ce = (ch0 + MAXE < e1g) ? (ch0 + MAXE) : e1g;
        const int cn = ce - ch0;

        if (t < 128) cnt[t] = 0;
        __syncthreads();
        // Phase 1: histogram of node-local ids
        for (int i = t; i < cn; i += 256)
            atomicAdd(&cnt[pairsP[ch0 + i] >> 17], 1);
        __syncthreads();
        // Phase 2: exclusive scan (Hillis-Steele over 128)
        {
            int v = (t < 128) ? cnt[t] : 0;
            int s = v;
            // use shared off as scratch via cnt copy
            if (t < 128) off[t] = v;
            __syncthreads();
            #pragma unroll
            for (int o = 1; o < 128; o <<= 1) {
                int u = 0;
                if (t < 128 && t >= o) u = off[t - o];
                __syncthreads();
                if (t < 128) off[t] += u;
                __syncthreads();
            }
            if (t < 128) {
                const int inc = off[t];
                off[t] = inc - v;           // exclusive
                cnt[t] = inc - v;           // cursor copy
                if (t == 127) off[128] = inc;
            }
            (void)s;
        }
        __syncthreads();
        // off[100] == total edges of first 100 ids (ids >=100 never occur)
        // Phase 3: scatter srcs grouped by node
        for (int i = t; i < cn; i += 256) {
            const int p = pairsP[ch0 + i];
            const int pos = atomicAdd(&cnt[p >> 17], 1);
            srt[pos] = p & 0x1FFFF;
        }
        __syncthreads();
        // Phase 4: per-node register-accumulated gather, c = lane
        for (int n = grp; n < BUCK_W; n += 8) {
            const int e0 = off[n];
            const int e1 = off[n + 1];
            float acc = 0.f, acc2 = 0.f;
            int e = e0;
            for (; e + 1 < e1; e += 2) {
                const int s0 = srt[e];
                const int s1 = srt[e + 1];
                const float v0 = bf2f(h1b[(size_t)s0 * HID + c]);
                const float v1 = bf2f(h1b[(size_t)s1 * HID + c]);
                acc += v0; acc2 += v1;
            }
            if (e < e1) acc += bf2f(h1b[(size_t)srt[e] * HID + c]);
            acc += acc2;
            if (acc != 0.f || true)
                out1[((size_t)b * BUCK_W + n) * HID + c] += acc;
        }
        __syncthreads();
    }
}

// ============ Layer 2 dense ============
__global__ __launch_bounds__(256) void k3_layer2_dense(
    const float* __restrict__ out1,
    const float* __restrict__ w2a_w, const float* __restrict__ w2a_b,
    const float* __restrict__ w2b_w, const float* __restrict__ w2b_b,
    ushort_t* __restrict__ h2b, float* __restrict__ out2)
{
    __shared__ float rs[64][33];
    __shared__ float h2s[64][17];
    __shared__ float wa[16][33];
    __shared__ float wb[16][17];

    const int t = threadIdx.x;
    const int node0 = blockIdx.x * 64;
    const int nrem = N_NODES - node0;

    for (int i = t; i < 16 * 32; i += 256)
        wa[i >> 5][i & 31] = w2a_w[i];
    if (t < 16 * 16) wb[t >> 4][t & 15] = w2b_w[t];
    for (int i = t; i < 64 * 32; i += 256) {
        int r = i >> 5, c = i & 31;
        float v = 0.f;
        if (r < nrem) v = out1[(size_t)(node0 + r) * HID + c];
        rs[r][c] = fmaxf(v, 0.f);
    }
    __syncthreads();

    const int o = t & 15;
    const int g = t >> 4;

    const float ba = w2a_b[o];
    float acc[4] = {};
    for (int c = 0; c < 32; ++c) {
        const float w = wa[o][c];
        #pragma unroll
        for (int j = 0; j < 4; ++j) acc[j] += rs[g * 4 + j][c] * w;
    }
    #pragma unroll
    for (int j = 0; j < 4; ++j) {
        const int ln = g * 4 + j;
        const float v = acc[j] + ba;
        h2s[ln][o] = v;
        if (ln < nrem) h2b[(size_t)(node0 + ln) * OUTC + o] = f2bf(v);
    }
    __syncthreads();

    const float bbv = w2b_b[o];
    float f[4] = {};
    for (int c = 0; c < 16; ++c) {
        const float w = wb[o][c];
        #pragma unroll
        for (int j = 0; j < 4; ++j) f[j] += h2s[g * 4 + j][c] * w;
    }
    #pragma unroll
    for (int j = 0; j < 4; ++j) {
        const int ln = g * 4 + j;
        if (ln < nrem) out2[(size_t)(node0 + ln) * OUTC + o] = f[j] + bbv;
    }
}

// ============ Aggregate layer 2 (sorted, register acc) + fused log_softmax ============
__global__ __launch_bounds__(256) void k_agg16_sm(const int* __restrict__ bstart,
                                                  const int* __restrict__ pairsP,
                                                  const ushort_t* __restrict__ h2b,
                                                  float* __restrict__ out2)
{
    __shared__ int cnt[128];
    __shared__ int off[129];
    __shared__ int srt[MAXE];
    const int t = threadIdx.x;
    const int b = blockIdx.x;
    const int c = t & 15;
    const int grp = t >> 4;                 // 16 groups of 16 lanes

    const int e0g = bstart[b];
    const int e1g = bstart[b + 1];

    for (int ch0 = e0g; ch0 < e1g; ch0 += MAXE) {
        const int ce = (ch0 + MAXE < e1g) ? (ch0 + MAXE) : e1g;
        const int cn = ce - ch0;
        const bool last = (ce == e1g);

        if (t < 128) cnt[t] = 0;
        __syncthreads();
        for (int i = t; i < cn; i += 256)
            atomicAdd(&cnt[pairsP[ch0 + i] >> 17], 1);
        __syncthreads();
        {
            int v = (t < 128) ? cnt[t] : 0;
            if (t < 128) off[t] = v;
            __syncthreads();
            #pragma unroll
            for (int o = 1; o < 128; o <<= 1) {
                int u = 0;
                if (t < 128 && t >= o) u = off[t - o];
                __syncthreads();
                if (t < 128) off[t] += u;
                __syncthreads();
            }
            if (t < 128) {
                const int inc = off[t];
                off[t] = inc - v;
                cnt[t] = inc - v;
                if (t == 127) off[128] = inc;
            }
        }
        __syncthreads();
        for (int i = t; i < cn; i += 256) {
            const int p = pairsP[ch0 + i];
            const int pos = atomicAdd(&cnt[p >> 17], 1);
            srt[pos] = p & 0x1FFFF;
        }
        __syncthreads();

        for (int n = grp; n < BUCK_W; n += 16) {
            const int e0 = off[n];
            const int e1 = off[n + 1];
            float acc = 0.f, acc2 = 0.f;
            int e = e0;
            for (; e + 1 < e1; e += 2) {
                const int s0 = srt[e];
                const int s1 = srt[e + 1];
                const float v0 = bf2f(h2b[(size_t)s0 * OUTC + c]);
                const float v1 = bf2f(h2b[(size_t)s1 * OUTC + c]);
                acc += v0; acc2 += v1;
            }
            if (e < e1) acc += bf2f(h2b[(size_t)srt[e] * OUTC + c]);
            acc += acc2;

            const size_t oidx = ((size_t)b * BUCK_W + n) * OUTC + c;
            if (!last) {
                out2[oidx] += acc;
            } else {
                const float val = out2[oidx] + acc;
                float m = val;
                #pragma unroll
                for (int o = 8; o > 0; o >>= 1)
                    m = fmaxf(m, __shfl_xor(m, o, 16));
                float s = expf(val - m);
                #pragma unroll
                for (int o = 8; o > 0; o >>= 1)
                    s += __shfl_xor(s, o, 16);
                const float lse = m + logf(s);
                out2[oidx] = val - lse;
            }
        }
        __syncthreads();
    }
}

extern "C" void kernel_launch(void* const* d_in, const int* in_sizes, int n_in,
                              void* d_out, int out_size, void* d_ws, size_t ws_size,
                              hipStream_t stream)
{
    const float* x      = (const float*)d_in[0];
    const float* w1a_w  = (const float*)d_in[1];
    const float* w1a_b  = (const float*)d_in[2];
    const float* w1b_w  = (const float*)d_in[3];
    const float* w1b_b  = (const float*)d_in[4];
    const float* w2a_w  = (const float*)d_in[5];
    const float* w2a_b  = (const float*)d_in[6];
    const float* w2b_w  = (const float*)d_in[7];
    const float* w2b_b  = (const float*)d_in[8];
    const int*   ei     = (const int*)d_in[9];
    float* out = (float*)d_out;

    // workspace (~31 MB)
    float*    out1   = (float*)d_ws;                              // 12.8 MB
    ushort_t* h1b    = (ushort_t*)(out1 + (size_t)N_NODES * HID); // 6.4 MB
    ushort_t* h2b    = h1b + (size_t)N_NODES * HID;               // 3.2 MB
    int*      pairsP = (int*)(h2b + (size_t)N_NODES * OUTC);      // 6.4 MB
    int*      bhist  = pairsP + N_EDGES;                          // 1 MB
    int*      boffB  = bhist + NBUCK * NBB;                       // 1 MB
    int*      btot   = boffB + NBUCK * NBB;                       // 1000
    int*      bstart = btot + NBUCK;                              // 1001

    k_cnt   <<<NBB, 256, 0, stream>>>(ei, bhist);
    k_scanH <<<NBUCK, 256, 0, stream>>>(bhist, boffB, btot);
    k_scanH2<<<1, 1024, 0, stream>>>(btot, bstart);
    k_scat  <<<NBB, 256, 0, stream>>>(ei, boffB, bstart, pairsP);

    k1_layer1_dense<<<(N_NODES + 255) / 256, 256, 0, stream>>>(x, w1a_w, w1a_b, w1b_w, w1b_b, h1b, out1);
    k_agg32<<<NBUCK, 256, 0, stream>>>(bstart, pairsP, h1b, out1);
    k3_layer2_dense<<<(N_NODES + 63) / 64, 256, 0, stream>>>(out1, w2a_w, w2a_b, w2b_w, w2b_b, h2b, out);
    k_agg16_sm<<<NBUCK, 256, 0, stream>>>(bstart, pairsP, h2b, out);
}